// Round 4
// baseline (545.197 us; speedup 1.0000x reference)
//
#include <hip/hip_runtime.h>

#define D_MODEL 2048
#define NHEADS  16
#define DK      128
#define BATCH   2
#define SEQ     2048
#define MTOT    (BATCH*SEQ)   // 4096 rows

typedef unsigned short u16;
typedef unsigned int   u32;
typedef __bf16 bf16x8 __attribute__((ext_vector_type(8)));
typedef float  f32x4  __attribute__((ext_vector_type(4)));

__device__ __forceinline__ float b2f(u16 u) {
  return __uint_as_float(((u32)u) << 16);
}
__device__ __forceinline__ u16 f2b(float f) {  // RNE fp32 -> bf16
  u32 x = __float_as_uint(f);
  x += 0x7fffu + ((x >> 16) & 1u);
  return (u16)(x >> 16);
}

// async global->LDS, 16B per lane; dest = wave-uniform base, HW adds lane*16
__device__ __forceinline__ void gl2lds16(const u16* g, u16* l) {
  __builtin_amdgcn_global_load_lds(
      (const __attribute__((address_space(1))) void*)g,
      (__attribute__((address_space(3))) void*)l, 16, 0, 0);
}

// ---------------- fp32 -> bf16 bulk convert ----------------
__global__ __launch_bounds__(256) void cvt_k(const float* __restrict__ in,
                                             u16* __restrict__ out, int n4) {
  int i = blockIdx.x * 256 + threadIdx.x;
  if (i >= n4) return;
  float4 v = ((const float4*)in)[i];
  u32 lo = (u32)f2b(v.x) | ((u32)f2b(v.y) << 16);
  u32 hi = (u32)f2b(v.z) | ((u32)f2b(v.w) << 16);
  ((uint2*)out)[i] = make_uint2(lo, hi);
}

// 4 weight matrices in one dispatch (blockIdx.y selects)
__global__ __launch_bounds__(256) void cvt4_k(const float* __restrict__ a, const float* __restrict__ b,
                                              const float* __restrict__ c, const float* __restrict__ d,
                                              u16* __restrict__ oa, u16* __restrict__ ob,
                                              u16* __restrict__ oc, u16* __restrict__ od, int n4) {
  int z = blockIdx.y;
  const float* in = (z == 0) ? a : (z == 1) ? b : (z == 2) ? c : d;
  u16* out = (z == 0) ? oa : (z == 1) ? ob : (z == 2) ? oc : od;
  int i = blockIdx.x * 256 + threadIdx.x;
  if (i >= n4) return;
  float4 v = ((const float4*)in)[i];
  u32 lo = (u32)f2b(v.x) | ((u32)f2b(v.y) << 16);
  u32 hi = (u32)f2b(v.z) | ((u32)f2b(v.w) << 16);
  ((uint2*)out)[i] = make_uint2(lo, hi);
}

// ---------------- GEMM: Y(M,N) = A(M,K) @ B(N,K)^T, bf16 MFMA ----------------
// 256x256 tile, BK=64, 512 threads (8 waves = 2M x 4N), per-wave 128x64 output
// (acc 8x4 frags). Staging-traffic analysis (R0/R1/R3): this kernel is bound
// by global->LDS staging bytes at ~7 TB/s (93% L2/L3-served); 256^2 halves
// traffic vs 256x128. Schedule = R1's lean skeleton (the only one that ran AT
// the traffic limit): per K-tile {issue 8 gl2lds16 into bufN -> s_waitcnt
// vmcnt(8) (counted, drains only on last tile) -> s_barrier -> 24 C++ b128
// frag reads + 4x16 MFMA (compiler-scheduled lgkmcnt; NO pins, NO
// sched_barrier - m141) -> s_barrier}. Double-buffered LDS 128 KiB,
// frag-major 1-KiB blocks (0 bank conflicts, linear DMA dest).
// XCD-aware bijective block swizzle (T1): nwg % 8 == 0 for both launches.
// mode 0: outf[row*N+col] = acc + bias[col]   (fp32, O-proj, N=2048)
// mode 1: fused QKV scatter, N=6144 (col>>11: 0=Q,1=K,2=V) -> (B,H,S,DK) bf16,
//         RoPE fused for Q/K (1/sqrt(DK) folded into Q).
__global__ __launch_bounds__(512, 2) void gemm256(const u16* __restrict__ A,
                                                  const u16* __restrict__ B,
                                                  const int M, const int N, const int K,
                                                  u16* __restrict__ outb,
                                                  float* __restrict__ outf,
                                                  const float* __restrict__ bias,
                                                  const int mode) {
  // per buffer: A = 32 blocks + B = 32 blocks (block = 16 rows x 32 k = 1 KiB)
  // = 64 KiB/buffer, x2 buffers = 128 KiB.
  __shared__ __align__(16) u16 smem[65536];

  const int t    = threadIdx.x;
  const int lane = t & 63;
  const int wave = t >> 6;                 // 0..7
  const int wm   = wave >> 2, wn = wave & 3;   // 2M x 4N
  const int quad = lane >> 4, l16 = lane & 15;

  // ---- XCD-aware bijective swizzle (nwg % 8 == 0 for all launches) ----
  const int nwg  = (int)(gridDim.x * gridDim.y);
  const int orig = (int)(blockIdx.y * gridDim.x + blockIdx.x);
  const int wgid = (orig & 7) * (nwg >> 3) + (orig >> 3);
  const int bx = wgid % (int)gridDim.x, by = wgid / (int)gridDim.x;
  const int m0 = by * 256, n0 = bx * 256;
  const int sr = lane & 15, sc = lane >> 4;   // staging: row-in-block, 16B col group

  // staging sites: site q (0..3), wave w stages A-block and B-block id = q*8+w.
  // block id -> (kc = id>>4, tile16 = id&15); 32 blocks each for A and B.
  const u16* aSrc[4]; u32 aDst[4];
  const u16* bSrc[4]; u32 bDst[4];
#pragma unroll
  for (int q = 0; q < 4; ++q) {
    int id = q * 8 + wave;                // 0..31
    int kc = id >> 4, t16 = id & 15;
    aSrc[q] = A + (size_t)(m0 + t16 * 16 + sr) * K + kc * 32 + sc * 8;
    aDst[q] = (u32)id * 512;
    bSrc[q] = B + (size_t)(n0 + t16 * 16 + sr) * K + kc * 32 + sc * 8;
    bDst[q] = 16384u + (u32)id * 512;
  }

  f32x4 acc[8][4] = {};
  const int NT = K >> 6;                  // 32 K-tiles at BK=64

  // prologue: stage tile 0 -> buffer 0 (8 loads/thread)
#pragma unroll
  for (int q = 0; q < 4; ++q) {
    gl2lds16(aSrc[q], smem + aDst[q]); aSrc[q] += 64;
    gl2lds16(bSrc[q], smem + bDst[q]); bSrc[q] += 64;
  }

  for (int tt = 0; tt < NT; ++tt) {
    u16* bufC = smem + (tt & 1) * 32768;         // holds tile tt
    u16* bufN = smem + ((tt & 1) ^ 1) * 32768;   // receives tile tt+1 (dead data)
    const bool more = (tt + 1 < NT);

    // issue tile tt+1 (8 loads), then counted gate: tt's 8 oldest landed.
    if (more) {
#pragma unroll
      for (int q = 0; q < 4; ++q) {
        gl2lds16(aSrc[q], bufN + aDst[q]); aSrc[q] += 64;
        gl2lds16(bSrc[q], bufN + bDst[q]); bSrc[q] += 64;
      }
      asm volatile("s_waitcnt vmcnt(8)" ::: "memory");
    } else {
      asm volatile("s_waitcnt vmcnt(0)" ::: "memory");
    }
    __builtin_amdgcn_s_barrier();                // all waves' tile-tt DMA landed

    const u16* Ab = bufC;
    const u16* Bb = bufC + 16384;
#pragma unroll
    for (int kc = 0; kc < 2; ++kc) {
      bf16x8 bfv[4];
#pragma unroll
      for (int j = 0; j < 4; ++j)
        bfv[j] = *(const bf16x8*)&Bb[(u32)(kc * 16 + wn * 4 + j) * 512 + lane * 8];
#pragma unroll
      for (int ih = 0; ih < 2; ++ih) {
        bf16x8 af[4];
#pragma unroll
        for (int ii = 0; ii < 4; ++ii)
          af[ii] = *(const bf16x8*)&Ab[(u32)(kc * 16 + wm * 8 + ih * 4 + ii) * 512 + lane * 8];
        __builtin_amdgcn_s_setprio(1);
#pragma unroll
        for (int ii = 0; ii < 4; ++ii)
#pragma unroll
          for (int j = 0; j < 4; ++j)
            acc[ih * 4 + ii][j] =
                __builtin_amdgcn_mfma_f32_16x16x32_bf16(af[ii], bfv[j], acc[ih * 4 + ii][j], 0, 0, 0);
        __builtin_amdgcn_s_setprio(0);
      }
    }
    __builtin_amdgcn_s_barrier();   // tile tt fully consumed; bufC free for tt+2
  }

  if (mode == 0) {
#pragma unroll
    for (int i = 0; i < 8; ++i)
#pragma unroll
      for (int j = 0; j < 4; ++j)
#pragma unroll
        for (int rr = 0; rr < 4; ++rr) {
          int row = m0 + wm * 128 + i * 16 + quad * 4 + rr;
          int col = n0 + wn * 64 + j * 16 + l16;
          outf[(size_t)row * N + col] = acc[i][j][rr] + bias[col];
        }
  } else {
    // QKV scatter + fused RoPE. tens uniform per block; h uniform per wave
    // (wave spans 64 cols within one 128-wide head).
    const int hcol = n0 + wn * 64;
    const int tens = hcol >> 11;               // 0=Q 1=K 2=V
    const int h    = (hcol >> 7) & 15;
    const int db   = hcol & 127;               // 0 or 64
    const bool doRope = (tens < 2);
    const float mult = (tens == 0) ? 0.08838834764831845f : 1.0f;  // 1/sqrt(DK) on Q
#pragma unroll
    for (int j = 0; j < 4; ++j) {
      const int d = db + j * 16 + l16;         // head-dim of this lane's column
      const float freq = exp2f(-0.20762050593045951f * (float)(d >> 1));
      const float sgn  = (d & 1) ? 1.f : -1.f;
#pragma unroll
      for (int i = 0; i < 8; ++i)
#pragma unroll
        for (int rr = 0; rr < 4; ++rr) {
          int row = m0 + wm * 128 + i * 16 + quad * 4 + rr;
          int b = row >> 11;
          int s = row & (SEQ - 1);
          float v = acc[i][j][rr];
          if (doRope) {
            float sn, cs;
            __sincosf((float)s * freq, &sn, &cs);
            float pv = __shfl_xor(v, 1);       // partner element of the (even,odd) pair
            v = (v * cs + sgn * pv * sn) * mult;
          }
          outb[(size_t)tens * 8388608 + (((size_t)(b * NHEADS + h)) * SEQ + s) * DK + d] = f2b(v);
        }
    }
  }
}

// ---------------- V transpose: (B,H,S,DK) -> (B,H,DK,S), bf16 ----------------
__global__ __launch_bounds__(256) void vt_k(const u16* __restrict__ V,
                                            u16* __restrict__ Vt) {
  constexpr int LDT = 72;
  __shared__ __align__(16) u16 tile[64 * LDT];
  const int s0 = blockIdx.x * 64, d0 = blockIdx.y * 64, bh = blockIdx.z;
  const u16* in = V + (size_t)bh * SEQ * DK;
  u16* out = Vt + (size_t)bh * DK * SEQ;
  const int t = threadIdx.x;
  const int r = t >> 3, cg = t & 7;
#pragma unroll
  for (int half = 0; half < 2; ++half) {
    uint4 v = *(const uint4*)(in + (size_t)(s0 + r + half * 32) * DK + d0 + cg * 8);
    *(uint4*)&tile[(r + half * 32) * LDT + cg * 8] = v;
  }
  __syncthreads();
#pragma unroll
  for (int half = 0; half < 2; ++half) {
    int d = (t >> 3) + half * 32;
    __align__(16) u16 tmp[8];
#pragma unroll
    for (int i = 0; i < 8; ++i) tmp[i] = tile[(cg * 8 + i) * LDT + d];
    *(uint4*)(out + (size_t)(d0 + d) * SEQ + s0 + cg * 8) = *(const uint4*)tmp;
  }
}

// ---------------- MFMA flash attention, causal, transposed-softmax ----------------
// Q: bf16 (B,H,S,DK), roped AND pre-scaled by 1/sqrt(DK). K: roped. Vt: (B,H,DK,S).
// out: bf16 (B,S,D_MODEL).
__global__ __launch_bounds__(256, 4) void attn_k(const u16* __restrict__ Q,
                                                 const u16* __restrict__ K,
                                                 const u16* __restrict__ Vt,
                                                 u16* __restrict__ out) {
  __shared__ __align__(16) u16 smem[8192 + 8192 + 4096];  // Ks, Vs, P = 40960B
  u16* Ks = smem;              // 16 blocks of 512: (nt*4+kc), frag-major
  u16* Vs = smem + 8192;       // 16 blocks of 512: (kcp*8+nt), frag-major

  const int t    = threadIdx.x;
  const int lane = t & 63;
  const int wave = t >> 6;
  const int quad = lane >> 4, l16 = lane & 15;
  u16* Psw = smem + 16384 + wave * 1024;        // 16q x 64k, swizzled
  const int pmask = (l16 & 7) << 3;             // XOR swizzle on key bits 3..5
  const int qt = (int)gridDim.x - 1 - (int)blockIdx.x;  // heavy blocks first
  const int bh = blockIdx.y;
  const size_t baseQK = (size_t)bh * SEQ * DK;
  const size_t baseV  = (size_t)bh * DK * SEQ;
  const int qw = qt * 64 + wave * 16;           // wave's first query row
  const int qglob = qw + l16;                   // this lane's query (transposed S)

  bf16x8 qf[4];
#pragma unroll
  for (int kc = 0; kc < 4; ++kc)
    qf[kc] = *(const bf16x8*)(Q + baseQK + (size_t)(qw + l16) * DK + kc * 32 + quad * 8);

  f32x4 oacc[8] = {};
  float m_run = -1e30f, l_run = 0.f;

  const int sr = lane & 15, sc = lane >> 4;
  const u16* kp[4]; u16* kd[4];
  const u16* vp[4]; u16* vd[4];
#pragma unroll
  for (int j = 0; j < 4; ++j) {
    int lin = wave * 4 + j;
    int knt = lin >> 2, kkc = lin & 3;
    kp[j] = K + baseQK + (size_t)(knt * 16 + sr) * DK + kkc * 32 + sc * 8;
    kd[j] = Ks + lin * 512;
    int vkc = lin >> 3, vnt = lin & 7;
    vp[j] = Vt + baseV + (size_t)(vnt * 16 + sr) * SEQ + vkc * 32 + sc * 8;
    vd[j] = Vs + lin * 512;
  }

  const int kend = (qt + 1) * 64;
  for (int k0 = 0; k0 < kend; k0 += 64) {
    __syncthreads();
#pragma unroll
    for (int j = 0; j < 4; ++j) gl2lds16(kp[j], kd[j]);
#pragma unroll
    for (int j = 0; j < 4; ++j) gl2lds16(vp[j], vd[j]);
#pragma unroll
    for (int j = 0; j < 4; ++j) { kp[j] += (size_t)64 * DK; vp[j] += 64; }
    __syncthreads();

    if (k0 >= qw + 16) continue;        // wave-uniform causal skip (tail tiles)

    // ---- S^T = K . Q^T : 4 tiles of 16(key)x16(q) ----
    f32x4 s[4] = {};
#pragma unroll
    for (int kc = 0; kc < 4; ++kc) {
#pragma unroll
      for (int nt = 0; nt < 4; ++nt) {
        bf16x8 kf = *(const bf16x8*)&Ks[(nt * 4 + kc) * 512 + lane * 8];
        s[nt] = __builtin_amdgcn_mfma_f32_16x16x32_bf16(kf, qf[kc], s[nt], 0, 0, 0);
      }
    }

    // ---- softmax (lane holds 16 keys for q = qglob) ----
    float p[4][4];
    float newm = m_run;
    if (k0 + 63 > qw) {  // diagonal tile: per-lane causal mask (wave-uniform branch)
#pragma unroll
      for (int nt = 0; nt < 4; ++nt)
#pragma unroll
        for (int r = 0; r < 4; ++r) {
          int key = k0 + nt * 16 + quad * 4 + r;
          float v = (key <= qglob) ? s[nt][r] : -1e30f;
          p[nt][r] = v;
          newm = fmaxf(newm, v);
        }
    } else {
#pragma unroll
      for (int nt = 0; nt < 4; ++nt)
#pragma unroll
        for (int r = 0; r < 4; ++r) {
          p[nt][r] = s[nt][r];
          newm = fmaxf(newm, s[nt][r]);
        }
    }
    newm = fmaxf(newm, __shfl_xor(newm, 16));
    newm = fmaxf(newm, __shfl_xor(newm, 32));
    float lsum = 0.f;
#pragma unroll
    for (int nt = 0; nt < 4; ++nt)
#pragma unroll
      for (int r = 0; r < 4; ++r) {
        float e = __expf(p[nt][r] - newm);
        p[nt][r] = e;
        lsum += e;
      }
    lsum += __shfl_xor(lsum, 16);
    lsum += __shfl_xor(lsum, 32);
    float alpha = __expf(m_run - newm);
    l_run = l_run * alpha + lsum;
    m_run = newm;

    // ---- P^T write (swizzled, per-wave region; 4 b64 writes) ----
#pragma unroll
    for (int nt = 0; nt < 4; ++nt) {
      u32 lo = (u32)f2b(p[nt][0]) | ((u32)f2b(p[nt][1]) << 16);
      u32 hi = (u32)f2b(p[nt][2]) | ((u32)f2b(p[nt][3]) << 16);
      *(uint2*)&Psw[l16 * 64 + ((nt * 16 + quad * 4) ^ pmask)] = make_uint2(lo, hi);
    }

    // ---- rescale O accumulator ----
#pragma unroll
    for (int r = 0; r < 4; ++r) {
      float av = __shfl(alpha, quad * 4 + r);
#pragma unroll
      for (int nt = 0; nt < 8; ++nt) oacc[nt][r] *= av;
    }

    // ---- PV: O[q][d] += P . V^T ----
#pragma unroll
    for (int kcp = 0; kcp < 2; ++kcp) {
      bf16x8 pf = *(const bf16x8*)&Psw[l16 * 64 + ((kcp * 32 + quad * 8) ^ pmask)];
#pragma unroll
      for (int nt = 0; nt < 8; ++nt) {
        bf16x8 vf = *(const bf16x8*)&Vs[(kcp * 8 + nt) * 512 + lane * 8];
        oacc[nt] = __builtin_amdgcn_mfma_f32_16x16x32_bf16(pf, vf, oacc[nt], 0, 0, 0);
      }
    }
  }

  // ---- epilogue: normalize, stage to LDS, coalesced b128 store ----
  constexpr int LDO = 136;
  float invl = 1.f / l_run;
  __syncthreads();
#pragma unroll
  for (int r = 0; r < 4; ++r) {
    float iv = __shfl(invl, quad * 4 + r);
#pragma unroll
    for (int nt = 0; nt < 8; ++nt)
      smem[(wave * 16 + quad * 4 + r) * LDO + nt * 16 + l16] = f2b(oacc[nt][r] * iv);
  }
  __syncthreads();
  const int b = bh >> 4, h = bh & 15;
#pragma unroll
  for (int pss = 0; pss < 4; ++pss) {
    int row = (t >> 4) + pss * 16;
    uint4 v = *(const uint4*)&smem[row * LDO + (t & 15) * 8];
    *(uint4*)(out + ((size_t)(b * SEQ + qt * 64 + row)) * D_MODEL + h * DK + (t & 15) * 8) = v;
  }
}

// ---------------- host-side orchestration ----------------
extern "C" void kernel_launch(void* const* d_in, const int* in_sizes, int n_in,
                              void* d_out, int out_size, void* d_ws, size_t ws_size,
                              hipStream_t stream) {
  const float* x  = (const float*)d_in[0];
  const float* wq = (const float*)d_in[1];
  const float* wk = (const float*)d_in[2];
  const float* wv = (const float*)d_in[3];
  const float* wo = (const float*)d_in[4];
  const float* bo = (const float*)d_in[5];
  float* out = (float*)d_out;

  char* wsb = (char*)d_ws;
  u16* xb    = (u16*)(wsb + 0);          // 16.78 MB (reused as attn output later)
  u16* wqb   = (u16*)(wsb + 16777216);   //  8.39 MB (wq/wk/wv contiguous => fused B)
  u16* wkb   = (u16*)(wsb + 25165824);
  u16* wvb   = (u16*)(wsb + 33554432);
  u16* wob   = (u16*)(wsb + 41943040);
  u16* Qb    = (u16*)(wsb + 50331648);   // Q/K/V contiguous => fused scatter dest
  u16* Kb    = (u16*)(wsb + 67108864);
  u16* Vb    = (u16*)(wsb + 83886080);
  u16* attnb = xb;                       // x's bf16 copy dead after QKV GEMM
  u16* Vtb   = wqb;                      // weights dead after QKV GEMM (16.78 MB span)

  // 1) convert inputs to bf16
  cvt_k<<<8192, 256, 0, stream>>>(x, xb, MTOT * D_MODEL / 4);
  cvt4_k<<<dim3(4096, 4), 256, 0, stream>>>(wq, wk, wv, wo, wqb, wkb, wvb, wob,
                                            D_MODEL * D_MODEL / 4);

  // 2) fused Q/K/V projection + RoPE (+Q scale): one GEMM, N=6144
  //    grid: 6144/256 x 4096/256 = 24 x 16 = 384 blocks (nwg % 8 == 0)
  gemm256<<<dim3(24, 16), 512, 0, stream>>>(xb, wqb, MTOT, 3 * D_MODEL, D_MODEL,
                                            Qb, nullptr, nullptr, 1);

  // 3) V transpose to (B,H,DK,S)
  vt_k<<<dim3(SEQ / 64, DK / 64, BATCH * NHEADS), 256, 0, stream>>>(Vb, Vtb);

  // 4) causal MFMA flash attention -> (B,S,D_MODEL) bf16
  attn_k<<<dim3(SEQ / 64, BATCH * NHEADS), 256, 0, stream>>>(Qb, Kb, Vtb, attnb);

  // 5) output projection + bias -> fp32 d_out
  //    grid: 2048/256 x 4096/256 = 8 x 16 = 128 blocks (nwg % 8 == 0)
  gemm256<<<dim3(8, 16), 512, 0, stream>>>(attnb, wob, MTOT, D_MODEL, D_MODEL,
                                           nullptr, out, bo, 0);
}

// Round 5
// 504.956 us; speedup vs baseline: 1.0797x; 1.0797x over previous
//
#include <hip/hip_runtime.h>

#define D_MODEL 2048
#define NHEADS  16
#define DK      128
#define BATCH   2
#define SEQ     2048
#define MTOT    (BATCH*SEQ)   // 4096 rows

typedef unsigned short u16;
typedef unsigned int   u32;
typedef __bf16 bf16x8 __attribute__((ext_vector_type(8)));
typedef float  f32x4  __attribute__((ext_vector_type(4)));

__device__ __forceinline__ float b2f(u16 u) {
  return __uint_as_float(((u32)u) << 16);
}
__device__ __forceinline__ u16 f2b(float f) {  // RNE fp32 -> bf16
  u32 x = __float_as_uint(f);
  x += 0x7fffu + ((x >> 16) & 1u);
  return (u16)(x >> 16);
}

// async global->LDS, 16B per lane; dest = wave-uniform base, HW adds lane*16
__device__ __forceinline__ void gl2lds16(const u16* g, u16* l) {
  __builtin_amdgcn_global_load_lds(
      (const __attribute__((address_space(1))) void*)g,
      (__attribute__((address_space(3))) void*)l, 16, 0, 0);
}

// ---------------- fp32 -> bf16 bulk convert ----------------
__global__ __launch_bounds__(256) void cvt_k(const float* __restrict__ in,
                                             u16* __restrict__ out, int n4) {
  int i = blockIdx.x * 256 + threadIdx.x;
  if (i >= n4) return;
  float4 v = ((const float4*)in)[i];
  u32 lo = (u32)f2b(v.x) | ((u32)f2b(v.y) << 16);
  u32 hi = (u32)f2b(v.z) | ((u32)f2b(v.w) << 16);
  ((uint2*)out)[i] = make_uint2(lo, hi);
}

// 4 weight matrices in one dispatch (blockIdx.y selects)
__global__ __launch_bounds__(256) void cvt4_k(const float* __restrict__ a, const float* __restrict__ b,
                                              const float* __restrict__ c, const float* __restrict__ d,
                                              u16* __restrict__ oa, u16* __restrict__ ob,
                                              u16* __restrict__ oc, u16* __restrict__ od, int n4) {
  int z = blockIdx.y;
  const float* in = (z == 0) ? a : (z == 1) ? b : (z == 2) ? c : d;
  u16* out = (z == 0) ? oa : (z == 1) ? ob : (z == 2) ? oc : od;
  int i = blockIdx.x * 256 + threadIdx.x;
  if (i >= n4) return;
  float4 v = ((const float4*)in)[i];
  u32 lo = (u32)f2b(v.x) | ((u32)f2b(v.y) << 16);
  u32 hi = (u32)f2b(v.z) | ((u32)f2b(v.w) << 16);
  ((uint2*)out)[i] = make_uint2(lo, hi);
}

// ---------------- GEMM: Y(M,N) = A(M,K) @ B(N,K)^T, bf16 MFMA ----------------
// R1 config (best measured: QKV 169us, O-proj 56us): 256x128 tile, BK=64,
// 512 threads (8 waves = 4M x 2N), per-wave 64x64 output. 3-stage pipeline:
// triple-buffered LDS (144 KiB), distance-2 prefetch via global_load_lds +
// counted s_waitcnt vmcnt(6) + raw s_barrier, setprio around MFMA clusters.
// Frag-major LDS blocks (16 rows x 32 k = 1 KiB): conflict-free both sides.
// NO XCD swizzle: with gridDim.x % 8 == 0 the HW round-robin already gives
// each XCD a fixed bx%8 residue class (3 B-panels, L2-resident) — R4's
// explicit swizzle DOUBLED FETCH_SIZE (94->176 MB) by streaming all B
// panels through each XCD's L2.
// mode 0: outf[row*N+col] = acc + bias[col]   (fp32, O-proj, N=2048)
// mode 1: fused QKV scatter, N=6144 (col>>11: 0=Q,1=K,2=V) -> (B,H,S,DK) bf16,
//         RoPE fused for Q/K (1/sqrt(DK) folded into Q).
__global__ __launch_bounds__(512, 2) void gemm256(const u16* __restrict__ A,
                                                  const u16* __restrict__ B,
                                                  const int M, const int N, const int K,
                                                  u16* __restrict__ outb,
                                                  float* __restrict__ outf,
                                                  const float* __restrict__ bias,
                                                  const int mode) {
  // per buffer: A = 32 blocks (16384 u16, 32 KiB), B = 16 blocks (8192 u16, 16 KiB)
  __shared__ __align__(16) u16 smem[3 * 24576];   // 144 KiB -> 1 block/CU

  const int t    = threadIdx.x;
  const int lane = t & 63;
  const int wave = t >> 6;                 // 0..7
  const int wm   = wave >> 1, wn = wave & 1;
  const int quad = lane >> 4, l16 = lane & 15;
  const int m0 = blockIdx.y * 256, n0 = blockIdx.x * 128;
  const int sr = lane & 15, sc = lane >> 4;   // staging: row-in-block, 16B col group

  // staging assignment: wave stages A-blocks {4w..4w+3}, B-blocks {2w,2w+1}
  const u16* agp[4]; u16* ald[4];
  const u16* bgp[2]; u16* bld[2];
#pragma unroll
  for (int q = 0; q < 4; ++q) {
    int a = wave * 4 + q;                 // 0..31
    int kc = a >> 4, mt = a & 15;         // block covers rows mt*16..+16, k kc*32..+32
    agp[q] = A + (size_t)(m0 + mt * 16 + sr) * K + kc * 32 + sc * 8;
    ald[q] = smem + a * 512;              // buffer-0 base (wave-uniform)
  }
#pragma unroll
  for (int q = 0; q < 2; ++q) {
    int b = wave * 2 + q;                 // 0..15
    int kc = b >> 3, nt = b & 7;
    bgp[q] = B + (size_t)(n0 + nt * 16 + sr) * K + kc * 32 + sc * 8;
    bld[q] = smem + 16384 + b * 512;
  }

  f32x4 acc[4][4] = {};
  const int NT = K >> 6;                  // 32 K-tiles at BK=64

  // prologue: stage tile 0 -> buf0, tile 1 -> buf1 (6 loads/thread each)
#pragma unroll
  for (int q = 0; q < 4; ++q) { gl2lds16(agp[q], ald[q]);         agp[q] += 64; }
#pragma unroll
  for (int q = 0; q < 2; ++q) { gl2lds16(bgp[q], bld[q]);         bgp[q] += 64; }
#pragma unroll
  for (int q = 0; q < 4; ++q) { gl2lds16(agp[q], ald[q] + 24576); agp[q] += 64; }
#pragma unroll
  for (int q = 0; q < 2; ++q) { gl2lds16(bgp[q], bld[q] + 24576); bgp[q] += 64; }

  int cur = 0;                            // buffer holding tile tt
  for (int tt = 0; tt < NT; ++tt) {
    // gate: all but the newest 6 loads (tile tt+1's) must be done => tile tt landed.
    // Never drains to 0 except on the final tile (T4: counted vmcnt).
    if (tt + 1 < NT) asm volatile("s_waitcnt vmcnt(6)" ::: "memory");
    else             asm volatile("s_waitcnt vmcnt(0)" ::: "memory");
    __builtin_amdgcn_s_barrier();
    asm volatile("" ::: "memory");        // keep LDS reads below the barrier

    // issue tile tt+2's loads into buf (cur+2)%3 (last read at iter tt-1,
    // protected by that iteration's trailing barrier) — stays in flight
    // across both barriers of this iteration.
    if (tt + 2 < NT) {
      int nb = cur + 2; if (nb >= 3) nb -= 3;
      const int off = nb * 24576;
#pragma unroll
      for (int q = 0; q < 4; ++q) { gl2lds16(agp[q], ald[q] + off); agp[q] += 64; }
#pragma unroll
      for (int q = 0; q < 2; ++q) { gl2lds16(bgp[q], bld[q] + off); bgp[q] += 64; }
    }

    const u16* As = smem + cur * 24576;
    const u16* Bs = As + 16384;
#pragma unroll
    for (int kc = 0; kc < 2; ++kc) {
      bf16x8 af[4], bfv[4];
#pragma unroll
      for (int i = 0; i < 4; ++i)
        af[i] = *(const bf16x8*)&As[(kc * 16 + wm * 4 + i) * 512 + lane * 8];
#pragma unroll
      for (int j = 0; j < 4; ++j)
        bfv[j] = *(const bf16x8*)&Bs[(kc * 8 + wn * 4 + j) * 512 + lane * 8];
      __builtin_amdgcn_s_setprio(1);
#pragma unroll
      for (int i = 0; i < 4; ++i)
#pragma unroll
        for (int j = 0; j < 4; ++j)
          acc[i][j] = __builtin_amdgcn_mfma_f32_16x16x32_bf16(af[i], bfv[j], acc[i][j], 0, 0, 0);
      __builtin_amdgcn_s_setprio(0);
    }
    asm volatile("" ::: "memory");        // keep LDS reads above the barrier
    __builtin_amdgcn_s_barrier();         // frags consumed -> cur may be overwritten next iter
    cur = cur + 1; if (cur >= 3) cur -= 3;
  }

  if (mode == 0) {
#pragma unroll
    for (int i = 0; i < 4; ++i)
#pragma unroll
      for (int j = 0; j < 4; ++j)
#pragma unroll
        for (int rr = 0; rr < 4; ++rr) {
          int row = m0 + wm * 64 + i * 16 + quad * 4 + rr;
          int col = n0 + wn * 64 + j * 16 + l16;
          outf[(size_t)row * N + col] = acc[i][j][rr] + bias[col];
        }
  } else {
    // QKV scatter + fused RoPE. tens/h uniform per block (n0 % 128 == 0).
    const int tens = n0 >> 11;                 // 0=Q 1=K 2=V
    const int h    = (n0 & 2047) >> 7;
    const bool doRope = (tens < 2);
    const float mult = (tens == 0) ? 0.08838834764831845f : 1.0f;  // 1/sqrt(DK) on Q
#pragma unroll
    for (int j = 0; j < 4; ++j) {
      const int d = wn * 64 + j * 16 + l16;    // head-dim of this lane's column
      const float freq = exp2f(-0.20762050593045951f * (float)(d >> 1));
      const float sgn  = (d & 1) ? 1.f : -1.f;
#pragma unroll
      for (int i = 0; i < 4; ++i)
#pragma unroll
        for (int rr = 0; rr < 4; ++rr) {
          int row = m0 + wm * 64 + i * 16 + quad * 4 + rr;
          int b = row >> 11;
          int s = row & (SEQ - 1);
          float v = acc[i][j][rr];
          if (doRope) {
            float sn, cs;
            __sincosf((float)s * freq, &sn, &cs);
            float pv = __shfl_xor(v, 1);       // partner element of the (even,odd) pair
            v = (v * cs + sgn * pv * sn) * mult;
          }
          outb[(size_t)tens * 8388608 + (((size_t)(b * NHEADS + h)) * SEQ + s) * DK + d] = f2b(v);
        }
    }
  }
}

// ---------------- V transpose: (B,H,S,DK) -> (B,H,DK,S), bf16 ----------------
__global__ __launch_bounds__(256) void vt_k(const u16* __restrict__ V,
                                            u16* __restrict__ Vt) {
  constexpr int LDT = 72;
  __shared__ __align__(16) u16 tile[64 * LDT];
  const int s0 = blockIdx.x * 64, d0 = blockIdx.y * 64, bh = blockIdx.z;
  const u16* in = V + (size_t)bh * SEQ * DK;
  u16* out = Vt + (size_t)bh * DK * SEQ;
  const int t = threadIdx.x;
  const int r = t >> 3, cg = t & 7;
#pragma unroll
  for (int half = 0; half < 2; ++half) {
    uint4 v = *(const uint4*)(in + (size_t)(s0 + r + half * 32) * DK + d0 + cg * 8);
    *(uint4*)&tile[(r + half * 32) * LDT + cg * 8] = v;
  }
  __syncthreads();
#pragma unroll
  for (int half = 0; half < 2; ++half) {
    int d = (t >> 3) + half * 32;
    __align__(16) u16 tmp[8];
#pragma unroll
    for (int i = 0; i < 8; ++i) tmp[i] = tile[(cg * 8 + i) * LDT + d];
    *(uint4*)(out + (size_t)(d0 + d) * SEQ + s0 + cg * 8) = *(const uint4*)tmp;
  }
}

// ---------------- MFMA flash attention, causal, transposed-softmax ----------------
// Q: bf16 (B,H,S,DK), roped AND pre-scaled by 1/sqrt(DK). K: roped. Vt: (B,H,DK,S).
// out: bf16 (B,S,D_MODEL).
// R5 upgrade: K/V DOUBLE-BUFFERED (80 KiB LDS, 2 blocks/CU) with counted
// vmcnt gate — the R1-GEMM skeleton. Old version drained vmcnt(0) twice per
// K-tile via __syncthreads (every tile paid full DMA latency serialized;
// attn was ~232us at ~150 TF, both pipes idle). New per-tile schedule:
//   {issue tile t+1's 8 DMAs into other buffer -> s_waitcnt vmcnt(8)
//    (counted; 0 only on last tile) -> s_barrier -> compute (causal-guarded)
//    -> s_barrier}.
__global__ __launch_bounds__(256, 2) void attn_k(const u16* __restrict__ Q,
                                                 const u16* __restrict__ K,
                                                 const u16* __restrict__ Vt,
                                                 u16* __restrict__ out) {
  // 2x Ks (8192 u16 each) + 2x Vs (8192 each) + P (8192) = 40960 u16 = 80 KiB
  __shared__ __align__(16) u16 smem[40960];

  const int t    = threadIdx.x;
  const int lane = t & 63;
  const int wave = t >> 6;
  const int quad = lane >> 4, l16 = lane & 15;
  u16* Psw = smem + 32768 + wave * 1024;        // 16q x 64k, swizzled
  const int pmask = (l16 & 7) << 3;             // XOR swizzle on key bits 3..5
  const int qt = (int)gridDim.x - 1 - (int)blockIdx.x;  // heavy blocks first
  const int bh = blockIdx.y;
  const size_t baseQK = (size_t)bh * SEQ * DK;
  const size_t baseV  = (size_t)bh * DK * SEQ;
  const int qw = qt * 64 + wave * 16;           // wave's first query row
  const int qglob = qw + l16;                   // this lane's query (transposed S)

  bf16x8 qf[4];
#pragma unroll
  for (int kc = 0; kc < 4; ++kc)
    qf[kc] = *(const bf16x8*)(Q + baseQK + (size_t)(qw + l16) * DK + kc * 32 + quad * 8);

  f32x4 oacc[8] = {};
  float m_run = -1e30f, l_run = 0.f;

  const int sr = lane & 15, sc = lane >> 4;
  const u16* kp[4]; u32 kdo[4];
  const u16* vp[4]; u32 vdo[4];
#pragma unroll
  for (int j = 0; j < 4; ++j) {
    int lin = wave * 4 + j;
    int knt = lin >> 2, kkc = lin & 3;
    kp[j] = K + baseQK + (size_t)(knt * 16 + sr) * DK + kkc * 32 + sc * 8;
    kdo[j] = (u32)lin * 512;                    // K block offset within K buffer
    int vkc = lin >> 3, vnt = lin & 7;
    vp[j] = Vt + baseV + (size_t)(vnt * 16 + sr) * SEQ + vkc * 32 + sc * 8;
    vdo[j] = 16384u + (u32)lin * 512;           // V block offset (V region base)
  }

  const int ntiles = qt + 1;
  // prologue: stage tile 0 -> buffer 0
#pragma unroll
  for (int j = 0; j < 4; ++j) { gl2lds16(kp[j], smem + kdo[j]); kp[j] += (size_t)64 * DK; }
#pragma unroll
  for (int j = 0; j < 4; ++j) { gl2lds16(vp[j], smem + vdo[j]); vp[j] += 64; }

  for (int tt = 0; tt < ntiles; ++tt) {
    const int cb = tt & 1;
    if (tt + 1 < ntiles) {
      const u32 nb = (u32)(cb ^ 1) * 8192;      // other buffer
#pragma unroll
      for (int j = 0; j < 4; ++j) { gl2lds16(kp[j], smem + nb + kdo[j]); kp[j] += (size_t)64 * DK; }
#pragma unroll
      for (int j = 0; j < 4; ++j) { gl2lds16(vp[j], smem + nb + vdo[j]); vp[j] += 64; }
      asm volatile("s_waitcnt vmcnt(8)" ::: "memory");   // tile tt's 8 landed
    } else {
      asm volatile("s_waitcnt vmcnt(0)" ::: "memory");
    }
    __builtin_amdgcn_s_barrier();               // all waves' tile-tt DMA landed

    const int k0 = tt * 64;
    if (k0 < qw + 16) {                         // wave-uniform causal guard
      const u16* Ks = smem + cb * 8192;
      const u16* Vs = smem + 16384 + cb * 8192;

      // ---- S^T = K . Q^T : 4 tiles of 16(key)x16(q) ----
      f32x4 s[4] = {};
      __builtin_amdgcn_s_setprio(1);
#pragma unroll
      for (int kc = 0; kc < 4; ++kc) {
#pragma unroll
        for (int nt = 0; nt < 4; ++nt) {
          bf16x8 kf = *(const bf16x8*)&Ks[(nt * 4 + kc) * 512 + lane * 8];
          s[nt] = __builtin_amdgcn_mfma_f32_16x16x32_bf16(kf, qf[kc], s[nt], 0, 0, 0);
        }
      }
      __builtin_amdgcn_s_setprio(0);

      // ---- softmax (lane holds 16 keys for q = qglob) ----
      float p[4][4];
      float newm = m_run;
      if (k0 + 63 > qw) {  // diagonal tile: per-lane causal mask (wave-uniform branch)
#pragma unroll
        for (int nt = 0; nt < 4; ++nt)
#pragma unroll
          for (int r = 0; r < 4; ++r) {
            int key = k0 + nt * 16 + quad * 4 + r;
            float v = (key <= qglob) ? s[nt][r] : -1e30f;
            p[nt][r] = v;
            newm = fmaxf(newm, v);
          }
      } else {
#pragma unroll
        for (int nt = 0; nt < 4; ++nt)
#pragma unroll
          for (int r = 0; r < 4; ++r) {
            p[nt][r] = s[nt][r];
            newm = fmaxf(newm, s[nt][r]);
          }
      }
      newm = fmaxf(newm, __shfl_xor(newm, 16));
      newm = fmaxf(newm, __shfl_xor(newm, 32));
      float lsum = 0.f;
#pragma unroll
      for (int nt = 0; nt < 4; ++nt)
#pragma unroll
        for (int r = 0; r < 4; ++r) {
          float e = __expf(p[nt][r] - newm);
          p[nt][r] = e;
          lsum += e;
        }
      lsum += __shfl_xor(lsum, 16);
      lsum += __shfl_xor(lsum, 32);
      float alpha = __expf(m_run - newm);
      l_run = l_run * alpha + lsum;
      m_run = newm;

      // ---- P^T write (swizzled, per-wave region; 4 b64 writes) ----
#pragma unroll
      for (int nt = 0; nt < 4; ++nt) {
        u32 lo = (u32)f2b(p[nt][0]) | ((u32)f2b(p[nt][1]) << 16);
        u32 hi = (u32)f2b(p[nt][2]) | ((u32)f2b(p[nt][3]) << 16);
        *(uint2*)&Psw[l16 * 64 + ((nt * 16 + quad * 4) ^ pmask)] = make_uint2(lo, hi);
      }

      // ---- rescale O accumulator ----
#pragma unroll
      for (int r = 0; r < 4; ++r) {
        float av = __shfl(alpha, quad * 4 + r);
#pragma unroll
        for (int nt = 0; nt < 8; ++nt) oacc[nt][r] *= av;
      }

      // ---- PV: O[q][d] += P . V^T ----
      __builtin_amdgcn_s_setprio(1);
#pragma unroll
      for (int kcp = 0; kcp < 2; ++kcp) {
        bf16x8 pf = *(const bf16x8*)&Psw[l16 * 64 + ((kcp * 32 + quad * 8) ^ pmask)];
#pragma unroll
        for (int nt = 0; nt < 8; ++nt) {
          bf16x8 vf = *(const bf16x8*)&Vs[(kcp * 8 + nt) * 512 + lane * 8];
          oacc[nt] = __builtin_amdgcn_mfma_f32_16x16x32_bf16(pf, vf, oacc[nt], 0, 0, 0);
        }
      }
      __builtin_amdgcn_s_setprio(0);
    }
    __builtin_amdgcn_s_barrier();   // all waves done reading buffer cb
  }

  // ---- epilogue: normalize, stage to LDS, coalesced b128 store ----
  constexpr int LDO = 136;
  float invl = 1.f / l_run;
  __syncthreads();
#pragma unroll
  for (int r = 0; r < 4; ++r) {
    float iv = __shfl(invl, quad * 4 + r);
#pragma unroll
    for (int nt = 0; nt < 8; ++nt)
      smem[(wave * 16 + quad * 4 + r) * LDO + nt * 16 + l16] = f2b(oacc[nt][r] * iv);
  }
  __syncthreads();
  const int b = bh >> 4, h = bh & 15;
#pragma unroll
  for (int pss = 0; pss < 4; ++pss) {
    int row = (t >> 4) + pss * 16;
    uint4 v = *(const uint4*)&smem[row * LDO + (t & 15) * 8];
    *(uint4*)(out + ((size_t)(b * SEQ + qt * 64 + row)) * D_MODEL + h * DK + (t & 15) * 8) = v;
  }
}

// ---------------- host-side orchestration ----------------
extern "C" void kernel_launch(void* const* d_in, const int* in_sizes, int n_in,
                              void* d_out, int out_size, void* d_ws, size_t ws_size,
                              hipStream_t stream) {
  const float* x  = (const float*)d_in[0];
  const float* wq = (const float*)d_in[1];
  const float* wk = (const float*)d_in[2];
  const float* wv = (const float*)d_in[3];
  const float* wo = (const float*)d_in[4];
  const float* bo = (const float*)d_in[5];
  float* out = (float*)d_out;

  char* wsb = (char*)d_ws;
  u16* xb    = (u16*)(wsb + 0);          // 16.78 MB (reused as attn output later)
  u16* wqb   = (u16*)(wsb + 16777216);   //  8.39 MB (wq/wk/wv contiguous => fused B)
  u16* wkb   = (u16*)(wsb + 25165824);
  u16* wvb   = (u16*)(wsb + 33554432);
  u16* wob   = (u16*)(wsb + 41943040);
  u16* Qb    = (u16*)(wsb + 50331648);   // Q/K/V contiguous => fused scatter dest
  u16* Kb    = (u16*)(wsb + 67108864);
  u16* Vb    = (u16*)(wsb + 83886080);
  u16* attnb = xb;                       // x's bf16 copy dead after QKV GEMM
  u16* Vtb   = wqb;                      // weights dead after QKV GEMM (16.78 MB span)

  // 1) convert inputs to bf16
  cvt_k<<<8192, 256, 0, stream>>>(x, xb, MTOT * D_MODEL / 4);
  cvt4_k<<<dim3(4096, 4), 256, 0, stream>>>(wq, wk, wv, wo, wqb, wkb, wvb, wob,
                                            D_MODEL * D_MODEL / 4);

  // 2) fused Q/K/V projection + RoPE (+Q scale): one GEMM, N=6144
  //    grid: 48 x 16 = 768 blocks = exactly 3 rounds of 256 CU
  gemm256<<<dim3(48, 16), 512, 0, stream>>>(xb, wqb, MTOT, 3 * D_MODEL, D_MODEL,
                                            Qb, nullptr, nullptr, 1);

  // 3) V transpose to (B,H,DK,S)
  vt_k<<<dim3(SEQ / 64, DK / 64, BATCH * NHEADS), 256, 0, stream>>>(Vb, Vtb);

  // 4) causal MFMA flash attention -> (B,S,D_MODEL) bf16
  attn_k<<<dim3(SEQ / 64, BATCH * NHEADS), 256, 0, stream>>>(Qb, Kb, Vtb, attnb);

  // 5) output projection + bias -> fp32 d_out
  //    grid: 16 x 16 = 256 blocks = exactly 1 round
  gemm256<<<dim3(16, 16), 512, 0, stream>>>(attnb, wob, MTOT, D_MODEL, D_MODEL,
                                            nullptr, out, bo, 0);
}

// Round 6
// 495.232 us; speedup vs baseline: 1.1009x; 1.0196x over previous
//
#include <hip/hip_runtime.h>

#define D_MODEL 2048
#define NHEADS  16
#define DK      128
#define BATCH   2
#define SEQ     2048
#define MTOT    (BATCH*SEQ)   // 4096 rows

typedef unsigned short u16;
typedef unsigned int   u32;
typedef __bf16 bf16x8 __attribute__((ext_vector_type(8)));
typedef float  f32x4  __attribute__((ext_vector_type(4)));

__device__ __forceinline__ float b2f(u16 u) {
  return __uint_as_float(((u32)u) << 16);
}
__device__ __forceinline__ u16 f2b(float f) {  // RNE fp32 -> bf16
  u32 x = __float_as_uint(f);
  x += 0x7fffu + ((x >> 16) & 1u);
  return (u16)(x >> 16);
}

// async global->LDS, 16B per lane; dest = wave-uniform base, HW adds lane*16
__device__ __forceinline__ void gl2lds16(const u16* g, u16* l) {
  __builtin_amdgcn_global_load_lds(
      (const __attribute__((address_space(1))) void*)g,
      (__attribute__((address_space(3))) void*)l, 16, 0, 0);
}

// ---------------- fp32 -> bf16 bulk convert ----------------
__global__ __launch_bounds__(256) void cvt_k(const float* __restrict__ in,
                                             u16* __restrict__ out, int n4) {
  int i = blockIdx.x * 256 + threadIdx.x;
  if (i >= n4) return;
  float4 v = ((const float4*)in)[i];
  u32 lo = (u32)f2b(v.x) | ((u32)f2b(v.y) << 16);
  u32 hi = (u32)f2b(v.z) | ((u32)f2b(v.w) << 16);
  ((uint2*)out)[i] = make_uint2(lo, hi);
}

// 4 weight matrices in one dispatch (blockIdx.y selects)
__global__ __launch_bounds__(256) void cvt4_k(const float* __restrict__ a, const float* __restrict__ b,
                                              const float* __restrict__ c, const float* __restrict__ d,
                                              u16* __restrict__ oa, u16* __restrict__ ob,
                                              u16* __restrict__ oc, u16* __restrict__ od, int n4) {
  int z = blockIdx.y;
  const float* in = (z == 0) ? a : (z == 1) ? b : (z == 2) ? c : d;
  u16* out = (z == 0) ? oa : (z == 1) ? ob : (z == 2) ? oc : od;
  int i = blockIdx.x * 256 + threadIdx.x;
  if (i >= n4) return;
  float4 v = ((const float4*)in)[i];
  u32 lo = (u32)f2b(v.x) | ((u32)f2b(v.y) << 16);
  u32 hi = (u32)f2b(v.z) | ((u32)f2b(v.w) << 16);
  ((uint2*)out)[i] = make_uint2(lo, hi);
}

// ---------------- GEMM: Y(M,N) = A(M,K) @ B(N,K)^T, bf16 MFMA ----------------
// R1 config (best measured QKV: 169us): 256x128 tile, BK=64, 512 threads
// (8 waves = 4M x 2N), per-wave 64x64 output. 3-stage pipeline: triple-
// buffered LDS (144 KiB), distance-2 prefetch via global_load_lds + counted
// s_waitcnt vmcnt(6) + raw s_barrier, setprio around MFMA clusters.
// Frag-major LDS blocks (16 rows x 32 k = 1 KiB): conflict-free both sides.
// mode 0: outf = acc + bias, via LDS-staged COALESCED float4 stores.
//   (R0 evidence _ord158: the old scalar-f32 store epilogue ran at 268 GB/s
//    and made the O-proj as slow as the 3x-bigger QKV GEMM.)
// mode 1: fused QKV scatter, N=6144 (col>>11: 0=Q,1=K,2=V) -> (B,H,S,DK) bf16,
//         RoPE fused for Q/K (1/sqrt(DK) folded into Q).
__global__ __launch_bounds__(512, 2) void gemm256(const u16* __restrict__ A,
                                                  const u16* __restrict__ B,
                                                  const int M, const int N, const int K,
                                                  u16* __restrict__ outb,
                                                  float* __restrict__ outf,
                                                  const float* __restrict__ bias,
                                                  const int mode) {
  // per buffer: A = 32 blocks (16384 u16, 32 KiB), B = 16 blocks (8192 u16, 16 KiB)
  __shared__ __align__(16) u16 smem[3 * 24576];   // 144 KiB -> 1 block/CU

  const int t    = threadIdx.x;
  const int lane = t & 63;
  const int wave = t >> 6;                 // 0..7
  const int wm   = wave >> 1, wn = wave & 1;
  const int quad = lane >> 4, l16 = lane & 15;
  const int m0 = blockIdx.y * 256, n0 = blockIdx.x * 128;
  const int sr = lane & 15, sc = lane >> 4;   // staging: row-in-block, 16B col group

  // staging assignment: wave stages A-blocks {4w..4w+3}, B-blocks {2w,2w+1}
  const u16* agp[4]; u16* ald[4];
  const u16* bgp[2]; u16* bld[2];
#pragma unroll
  for (int q = 0; q < 4; ++q) {
    int a = wave * 4 + q;                 // 0..31
    int kc = a >> 4, mt = a & 15;         // block covers rows mt*16..+16, k kc*32..+32
    agp[q] = A + (size_t)(m0 + mt * 16 + sr) * K + kc * 32 + sc * 8;
    ald[q] = smem + a * 512;              // buffer-0 base (wave-uniform)
  }
#pragma unroll
  for (int q = 0; q < 2; ++q) {
    int b = wave * 2 + q;                 // 0..15
    int kc = b >> 3, nt = b & 7;
    bgp[q] = B + (size_t)(n0 + nt * 16 + sr) * K + kc * 32 + sc * 8;
    bld[q] = smem + 16384 + b * 512;
  }

  f32x4 acc[4][4] = {};
  const int NT = K >> 6;                  // 32 K-tiles at BK=64

  // prologue: stage tile 0 -> buf0, tile 1 -> buf1 (6 loads/thread each)
#pragma unroll
  for (int q = 0; q < 4; ++q) { gl2lds16(agp[q], ald[q]);         agp[q] += 64; }
#pragma unroll
  for (int q = 0; q < 2; ++q) { gl2lds16(bgp[q], bld[q]);         bgp[q] += 64; }
#pragma unroll
  for (int q = 0; q < 4; ++q) { gl2lds16(agp[q], ald[q] + 24576); agp[q] += 64; }
#pragma unroll
  for (int q = 0; q < 2; ++q) { gl2lds16(bgp[q], bld[q] + 24576); bgp[q] += 64; }

  int cur = 0;                            // buffer holding tile tt
  for (int tt = 0; tt < NT; ++tt) {
    // gate: all but the newest 6 loads (tile tt+1's) must be done => tile tt landed.
    // Never drains to 0 except on the final tile (T4: counted vmcnt).
    if (tt + 1 < NT) asm volatile("s_waitcnt vmcnt(6)" ::: "memory");
    else             asm volatile("s_waitcnt vmcnt(0)" ::: "memory");
    __builtin_amdgcn_s_barrier();
    asm volatile("" ::: "memory");        // keep LDS reads below the barrier

    // issue tile tt+2's loads into buf (cur+2)%3 (last read at iter tt-1,
    // protected by that iteration's trailing barrier) — stays in flight
    // across both barriers of this iteration.
    if (tt + 2 < NT) {
      int nb = cur + 2; if (nb >= 3) nb -= 3;
      const int off = nb * 24576;
#pragma unroll
      for (int q = 0; q < 4; ++q) { gl2lds16(agp[q], ald[q] + off); agp[q] += 64; }
#pragma unroll
      for (int q = 0; q < 2; ++q) { gl2lds16(bgp[q], bld[q] + off); bgp[q] += 64; }
    }

    const u16* As = smem + cur * 24576;
    const u16* Bs = As + 16384;
#pragma unroll
    for (int kc = 0; kc < 2; ++kc) {
      bf16x8 af[4], bfv[4];
#pragma unroll
      for (int i = 0; i < 4; ++i)
        af[i] = *(const bf16x8*)&As[(kc * 16 + wm * 4 + i) * 512 + lane * 8];
#pragma unroll
      for (int j = 0; j < 4; ++j)
        bfv[j] = *(const bf16x8*)&Bs[(kc * 8 + wn * 4 + j) * 512 + lane * 8];
      __builtin_amdgcn_s_setprio(1);
#pragma unroll
      for (int i = 0; i < 4; ++i)
#pragma unroll
        for (int j = 0; j < 4; ++j)
          acc[i][j] = __builtin_amdgcn_mfma_f32_16x16x32_bf16(af[i], bfv[j], acc[i][j], 0, 0, 0);
      __builtin_amdgcn_s_setprio(0);
    }
    asm volatile("" ::: "memory");        // keep LDS reads above the barrier
    __builtin_amdgcn_s_barrier();         // frags consumed -> cur may be overwritten next iter
    cur = cur + 1; if (cur >= 3) cur -= 3;
  }

  if (mode == 0) {
    // ---- coalesced epilogue: LDS-stage fp32 tile (stride 132: 16B-aligned
    // rows, bank rotation 4/row => <=2-way aliasing = free), then float4
    // stores with bias folded in. 256x132x4B = 135168 <= 147456 B. ----
    constexpr int LDW = 132;
    float* lf = (float*)smem;
#pragma unroll
    for (int i = 0; i < 4; ++i)
#pragma unroll
      for (int j = 0; j < 4; ++j)
#pragma unroll
        for (int rr = 0; rr < 4; ++rr) {
          int row = wm * 64 + i * 16 + quad * 4 + rr;
          int col = wn * 64 + j * 16 + l16;
          lf[row * LDW + col] = acc[i][j][rr];
        }
    __builtin_amdgcn_s_barrier();
    const int cg  = t & 31;               // 32 float4 groups cover 128 cols
    const int rw0 = t >> 5;               // 16 rows per pass
    float4 bv = *(const float4*)&bias[n0 + cg * 4];
#pragma unroll
    for (int ps = 0; ps < 16; ++ps) {
      int row = rw0 + ps * 16;
      const float* p = &lf[row * LDW + cg * 4];
      float4 v;
      v.x = p[0] + bv.x; v.y = p[1] + bv.y; v.z = p[2] + bv.z; v.w = p[3] + bv.w;
      *(float4*)&outf[(size_t)(m0 + row) * N + n0 + cg * 4] = v;
    }
  } else {
    // QKV scatter + fused RoPE. tens/h uniform per block (n0 % 128 == 0).
    const int tens = n0 >> 11;                 // 0=Q 1=K 2=V
    const int h    = (n0 & 2047) >> 7;
    const bool doRope = (tens < 2);
    const float mult = (tens == 0) ? 0.08838834764831845f : 1.0f;  // 1/sqrt(DK) on Q
#pragma unroll
    for (int j = 0; j < 4; ++j) {
      const int d = wn * 64 + j * 16 + l16;    // head-dim of this lane's column
      const float freq = exp2f(-0.20762050593045951f * (float)(d >> 1));
      const float sgn  = (d & 1) ? 1.f : -1.f;
#pragma unroll
      for (int i = 0; i < 4; ++i)
#pragma unroll
        for (int rr = 0; rr < 4; ++rr) {
          int row = m0 + wm * 64 + i * 16 + quad * 4 + rr;
          int b = row >> 11;
          int s = row & (SEQ - 1);
          float v = acc[i][j][rr];
          if (doRope) {
            float sn, cs;
            __sincosf((float)s * freq, &sn, &cs);
            float pv = __shfl_xor(v, 1);       // partner element of the (even,odd) pair
            v = (v * cs + sgn * pv * sn) * mult;
          }
          outb[(size_t)tens * 8388608 + (((size_t)(b * NHEADS + h)) * SEQ + s) * DK + d] = f2b(v);
        }
    }
  }
}

// ---------------- V transpose: (B,H,S,DK) -> (B,H,DK,S), bf16 ----------------
__global__ __launch_bounds__(256) void vt_k(const u16* __restrict__ V,
                                            u16* __restrict__ Vt) {
  constexpr int LDT = 72;
  __shared__ __align__(16) u16 tile[64 * LDT];
  const int s0 = blockIdx.x * 64, d0 = blockIdx.y * 64, bh = blockIdx.z;
  const u16* in = V + (size_t)bh * SEQ * DK;
  u16* out = Vt + (size_t)bh * DK * SEQ;
  const int t = threadIdx.x;
  const int r = t >> 3, cg = t & 7;
#pragma unroll
  for (int half = 0; half < 2; ++half) {
    uint4 v = *(const uint4*)(in + (size_t)(s0 + r + half * 32) * DK + d0 + cg * 8);
    *(uint4*)&tile[(r + half * 32) * LDT + cg * 8] = v;
  }
  __syncthreads();
#pragma unroll
  for (int half = 0; half < 2; ++half) {
    int d = (t >> 3) + half * 32;
    __align__(16) u16 tmp[8];
#pragma unroll
    for (int i = 0; i < 8; ++i) tmp[i] = tile[(cg * 8 + i) * LDT + d];
    *(uint4*)(out + (size_t)(d0 + d) * SEQ + s0 + cg * 8) = *(const uint4*)tmp;
  }
}

// ---------------- MFMA flash attention, causal, transposed-softmax ----------------
// Q: bf16 (B,H,S,DK), roped AND pre-scaled by 1/sqrt(DK). K: roped. Vt: (B,H,DK,S).
// out: bf16 (B,S,D_MODEL).  (R1 version: 40 KB LDS, 4 blocks/CU — R5's
// double-buffer halved residency for no net gain; reverted.)
__global__ __launch_bounds__(256, 4) void attn_k(const u16* __restrict__ Q,
                                                 const u16* __restrict__ K,
                                                 const u16* __restrict__ Vt,
                                                 u16* __restrict__ out) {
  __shared__ __align__(16) u16 smem[8192 + 8192 + 4096];  // Ks, Vs, P = 40960B
  u16* Ks = smem;              // 16 blocks of 512: (nt*4+kc), frag-major
  u16* Vs = smem + 8192;       // 16 blocks of 512: (kcp*8+nt), frag-major

  const int t    = threadIdx.x;
  const int lane = t & 63;
  const int wave = t >> 6;
  const int quad = lane >> 4, l16 = lane & 15;
  u16* Psw = smem + 16384 + wave * 1024;        // 16q x 64k, swizzled
  const int pmask = (l16 & 7) << 3;             // XOR swizzle on key bits 3..5
  const int qt = (int)gridDim.x - 1 - (int)blockIdx.x;  // heavy blocks first
  const int bh = blockIdx.y;
  const size_t baseQK = (size_t)bh * SEQ * DK;
  const size_t baseV  = (size_t)bh * DK * SEQ;
  const int qw = qt * 64 + wave * 16;           // wave's first query row
  const int qglob = qw + l16;                   // this lane's query (transposed S)

  bf16x8 qf[4];
#pragma unroll
  for (int kc = 0; kc < 4; ++kc)
    qf[kc] = *(const bf16x8*)(Q + baseQK + (size_t)(qw + l16) * DK + kc * 32 + quad * 8);

  f32x4 oacc[8] = {};
  float m_run = -1e30f, l_run = 0.f;

  const int sr = lane & 15, sc = lane >> 4;
  const u16* kp[4]; u16* kd[4];
  const u16* vp[4]; u16* vd[4];
#pragma unroll
  for (int j = 0; j < 4; ++j) {
    int lin = wave * 4 + j;
    int knt = lin >> 2, kkc = lin & 3;
    kp[j] = K + baseQK + (size_t)(knt * 16 + sr) * DK + kkc * 32 + sc * 8;
    kd[j] = Ks + lin * 512;
    int vkc = lin >> 3, vnt = lin & 7;
    vp[j] = Vt + baseV + (size_t)(vnt * 16 + sr) * SEQ + vkc * 32 + sc * 8;
    vd[j] = Vs + lin * 512;
  }

  const int kend = (qt + 1) * 64;
  for (int k0 = 0; k0 < kend; k0 += 64) {
    __syncthreads();
#pragma unroll
    for (int j = 0; j < 4; ++j) gl2lds16(kp[j], kd[j]);
#pragma unroll
    for (int j = 0; j < 4; ++j) gl2lds16(vp[j], vd[j]);
#pragma unroll
    for (int j = 0; j < 4; ++j) { kp[j] += (size_t)64 * DK; vp[j] += 64; }
    __syncthreads();

    if (k0 >= qw + 16) continue;        // wave-uniform causal skip (tail tiles)

    // ---- S^T = K . Q^T : 4 tiles of 16(key)x16(q) ----
    f32x4 s[4] = {};
#pragma unroll
    for (int kc = 0; kc < 4; ++kc) {
#pragma unroll
      for (int nt = 0; nt < 4; ++nt) {
        bf16x8 kf = *(const bf16x8*)&Ks[(nt * 4 + kc) * 512 + lane * 8];
        s[nt] = __builtin_amdgcn_mfma_f32_16x16x32_bf16(kf, qf[kc], s[nt], 0, 0, 0);
      }
    }

    // ---- softmax (lane holds 16 keys for q = qglob) ----
    float p[4][4];
    float newm = m_run;
    if (k0 + 63 > qw) {  // diagonal tile: per-lane causal mask (wave-uniform branch)
#pragma unroll
      for (int nt = 0; nt < 4; ++nt)
#pragma unroll
        for (int r = 0; r < 4; ++r) {
          int key = k0 + nt * 16 + quad * 4 + r;
          float v = (key <= qglob) ? s[nt][r] : -1e30f;
          p[nt][r] = v;
          newm = fmaxf(newm, v);
        }
    } else {
#pragma unroll
      for (int nt = 0; nt < 4; ++nt)
#pragma unroll
        for (int r = 0; r < 4; ++r) {
          p[nt][r] = s[nt][r];
          newm = fmaxf(newm, s[nt][r]);
        }
    }
    newm = fmaxf(newm, __shfl_xor(newm, 16));
    newm = fmaxf(newm, __shfl_xor(newm, 32));
    float lsum = 0.f;
#pragma unroll
    for (int nt = 0; nt < 4; ++nt)
#pragma unroll
      for (int r = 0; r < 4; ++r) {
        float e = __expf(p[nt][r] - newm);
        p[nt][r] = e;
        lsum += e;
      }
    lsum += __shfl_xor(lsum, 16);
    lsum += __shfl_xor(lsum, 32);
    float alpha = __expf(m_run - newm);
    l_run = l_run * alpha + lsum;
    m_run = newm;

    // ---- P^T write (swizzled, per-wave region; 4 b64 writes) ----
#pragma unroll
    for (int nt = 0; nt < 4; ++nt) {
      u32 lo = (u32)f2b(p[nt][0]) | ((u32)f2b(p[nt][1]) << 16);
      u32 hi = (u32)f2b(p[nt][2]) | ((u32)f2b(p[nt][3]) << 16);
      *(uint2*)&Psw[l16 * 64 + ((nt * 16 + quad * 4) ^ pmask)] = make_uint2(lo, hi);
    }

    // ---- rescale O accumulator ----
#pragma unroll
    for (int r = 0; r < 4; ++r) {
      float av = __shfl(alpha, quad * 4 + r);
#pragma unroll
      for (int nt = 0; nt < 8; ++nt) oacc[nt][r] *= av;
    }

    // ---- PV: O[q][d] += P . V^T ----
#pragma unroll
    for (int kcp = 0; kcp < 2; ++kcp) {
      bf16x8 pf = *(const bf16x8*)&Psw[l16 * 64 + ((kcp * 32 + quad * 8) ^ pmask)];
#pragma unroll
      for (int nt = 0; nt < 8; ++nt) {
        bf16x8 vf = *(const bf16x8*)&Vs[(kcp * 8 + nt) * 512 + lane * 8];
        oacc[nt] = __builtin_amdgcn_mfma_f32_16x16x32_bf16(pf, vf, oacc[nt], 0, 0, 0);
      }
    }
  }

  // ---- epilogue: normalize, stage to LDS, coalesced b128 store ----
  constexpr int LDO = 136;
  float invl = 1.f / l_run;
  __syncthreads();
#pragma unroll
  for (int r = 0; r < 4; ++r) {
    float iv = __shfl(invl, quad * 4 + r);
#pragma unroll
    for (int nt = 0; nt < 8; ++nt)
      smem[(wave * 16 + quad * 4 + r) * LDO + nt * 16 + l16] = f2b(oacc[nt][r] * iv);
  }
  __syncthreads();
  const int b = bh >> 4, h = bh & 15;
#pragma unroll
  for (int pss = 0; pss < 4; ++pss) {
    int row = (t >> 4) + pss * 16;
    uint4 v = *(const uint4*)&smem[row * LDO + (t & 15) * 8];
    *(uint4*)(out + ((size_t)(b * SEQ + qt * 64 + row)) * D_MODEL + h * DK + (t & 15) * 8) = v;
  }
}

// ---------------- host-side orchestration ----------------
extern "C" void kernel_launch(void* const* d_in, const int* in_sizes, int n_in,
                              void* d_out, int out_size, void* d_ws, size_t ws_size,
                              hipStream_t stream) {
  const float* x  = (const float*)d_in[0];
  const float* wq = (const float*)d_in[1];
  const float* wk = (const float*)d_in[2];
  const float* wv = (const float*)d_in[3];
  const float* wo = (const float*)d_in[4];
  const float* bo = (const float*)d_in[5];
  float* out = (float*)d_out;

  char* wsb = (char*)d_ws;
  u16* xb    = (u16*)(wsb + 0);          // 16.78 MB (reused as attn output later)
  u16* wqb   = (u16*)(wsb + 16777216);   //  8.39 MB (wq/wk/wv contiguous => fused B)
  u16* wkb   = (u16*)(wsb + 25165824);
  u16* wvb   = (u16*)(wsb + 33554432);
  u16* wob   = (u16*)(wsb + 41943040);
  u16* Qb    = (u16*)(wsb + 50331648);   // Q/K/V contiguous => fused scatter dest
  u16* Kb    = (u16*)(wsb + 67108864);
  u16* Vb    = (u16*)(wsb + 83886080);
  u16* attnb = xb;                       // x's bf16 copy dead after QKV GEMM
  u16* Vtb   = wqb;                      // weights dead after QKV GEMM (16.78 MB span)

  // 1) convert inputs to bf16
  cvt_k<<<8192, 256, 0, stream>>>(x, xb, MTOT * D_MODEL / 4);
  cvt4_k<<<dim3(4096, 4), 256, 0, stream>>>(wq, wk, wv, wo, wqb, wkb, wvb, wob,
                                            D_MODEL * D_MODEL / 4);

  // 2) fused Q/K/V projection + RoPE (+Q scale): one GEMM, N=6144
  //    grid: 48 x 16 = 768 blocks = exactly 3 rounds of 256 CU
  gemm256<<<dim3(48, 16), 512, 0, stream>>>(xb, wqb, MTOT, 3 * D_MODEL, D_MODEL,
                                            Qb, nullptr, nullptr, 1);

  // 3) V transpose to (B,H,DK,S)
  vt_k<<<dim3(SEQ / 64, DK / 64, BATCH * NHEADS), 256, 0, stream>>>(Vb, Vtb);

  // 4) causal MFMA flash attention -> (B,S,D_MODEL) bf16
  attn_k<<<dim3(SEQ / 64, BATCH * NHEADS), 256, 0, stream>>>(Qb, Kb, Vtb, attnb);

  // 5) output projection + bias -> fp32 d_out
  //    grid: 16 x 16 = 256 blocks = exactly 1 round
  gemm256<<<dim3(16, 16), 512, 0, stream>>>(attnb, wob, MTOT, D_MODEL, D_MODEL,
                                            nullptr, out, bo, 0);
}

// Round 9
// 450.793 us; speedup vs baseline: 1.2094x; 1.0986x over previous
//
#include <hip/hip_runtime.h>

#define D_MODEL 2048
#define NHEADS  16
#define DK      128
#define BATCH   2
#define SEQ     2048
#define MTOT    (BATCH*SEQ)   // 4096 rows

typedef unsigned short u16;
typedef unsigned int   u32;
typedef __bf16 bf16x8 __attribute__((ext_vector_type(8)));
typedef float  f32x4  __attribute__((ext_vector_type(4)));

__device__ __forceinline__ float b2f(u16 u) {
  return __uint_as_float(((u32)u) << 16);
}
__device__ __forceinline__ u16 f2b(float f) {  // RNE fp32 -> bf16
  u32 x = __float_as_uint(f);
  x += 0x7fffu + ((x >> 16) & 1u);
  return (u16)(x >> 16);
}

// async global->LDS, 16B per lane; dest = wave-uniform base, HW adds lane*16
__device__ __forceinline__ void gl2lds16(const u16* g, u16* l) {
  __builtin_amdgcn_global_load_lds(
      (const __attribute__((address_space(1))) void*)g,
      (__attribute__((address_space(3))) void*)l, 16, 0, 0);
}

// ---------------- fp32 -> bf16 bulk convert ----------------
__global__ __launch_bounds__(256) void cvt_k(const float* __restrict__ in,
                                             u16* __restrict__ out, int n4) {
  int i = blockIdx.x * 256 + threadIdx.x;
  if (i >= n4) return;
  float4 v = ((const float4*)in)[i];
  u32 lo = (u32)f2b(v.x) | ((u32)f2b(v.y) << 16);
  u32 hi = (u32)f2b(v.z) | ((u32)f2b(v.w) << 16);
  ((uint2*)out)[i] = make_uint2(lo, hi);
}

// 4 weight matrices in one dispatch (blockIdx.y selects)
__global__ __launch_bounds__(256) void cvt4_k(const float* __restrict__ a, const float* __restrict__ b,
                                              const float* __restrict__ c, const float* __restrict__ d,
                                              u16* __restrict__ oa, u16* __restrict__ ob,
                                              u16* __restrict__ oc, u16* __restrict__ od, int n4) {
  int z = blockIdx.y;
  const float* in = (z == 0) ? a : (z == 1) ? b : (z == 2) ? c : d;
  u16* out = (z == 0) ? oa : (z == 1) ? ob : (z == 2) ? oc : od;
  int i = blockIdx.x * 256 + threadIdx.x;
  if (i >= n4) return;
  float4 v = ((const float4*)in)[i];
  u32 lo = (u32)f2b(v.x) | ((u32)f2b(v.y) << 16);
  u32 hi = (u32)f2b(v.z) | ((u32)f2b(v.w) << 16);
  ((uint2*)out)[i] = make_uint2(lo, hi);
}

// ---------------- GEMM: Y(M,N) = A(M,K) @ B(N,K)^T, bf16 MFMA ----------------
// R1 config (best measured QKV: 169us): 256x128 tile, BK=64, 512 threads
// (8 waves = 4M x 2N), per-wave 64x64 output. 3-stage pipeline: triple-
// buffered LDS (144 KiB), distance-2 prefetch via global_load_lds + counted
// s_waitcnt vmcnt(6) + raw s_barrier, setprio around MFMA clusters.
// Frag-major LDS blocks (16 rows x 32 k = 1 KiB): conflict-free both sides.
// mode 0: outf = acc + bias, via LDS-staged coalesced float4 stores.
// mode 1: fused QKV scatter, N=6144 (col>>11: 0=Q,1=K,2=V) -> (B,H,S,DK) bf16,
//         RoPE fused for Q/K (1/sqrt(DK) folded into Q).
__global__ __launch_bounds__(512, 2) void gemm256(const u16* __restrict__ A,
                                                  const u16* __restrict__ B,
                                                  const int M, const int N, const int K,
                                                  u16* __restrict__ outb,
                                                  float* __restrict__ outf,
                                                  const float* __restrict__ bias,
                                                  const int mode) {
  // per buffer: A = 32 blocks (16384 u16, 32 KiB), B = 16 blocks (8192 u16, 16 KiB)
  __shared__ __align__(16) u16 smem[3 * 24576];   // 144 KiB -> 1 block/CU

  const int t    = threadIdx.x;
  const int lane = t & 63;
  const int wave = t >> 6;                 // 0..7
  const int wm   = wave >> 1, wn = wave & 1;
  const int quad = lane >> 4, l16 = lane & 15;
  const int m0 = blockIdx.y * 256, n0 = blockIdx.x * 128;
  const int sr = lane & 15, sc = lane >> 4;   // staging: row-in-block, 16B col group

  // staging assignment: wave stages A-blocks {4w..4w+3}, B-blocks {2w,2w+1}
  const u16* agp[4]; u16* ald[4];
  const u16* bgp[2]; u16* bld[2];
#pragma unroll
  for (int q = 0; q < 4; ++q) {
    int a = wave * 4 + q;                 // 0..31
    int kc = a >> 4, mt = a & 15;         // block covers rows mt*16..+16, k kc*32..+32
    agp[q] = A + (size_t)(m0 + mt * 16 + sr) * K + kc * 32 + sc * 8;
    ald[q] = smem + a * 512;              // buffer-0 base (wave-uniform)
  }
#pragma unroll
  for (int q = 0; q < 2; ++q) {
    int b = wave * 2 + q;                 // 0..15
    int kc = b >> 3, nt = b & 7;
    bgp[q] = B + (size_t)(n0 + nt * 16 + sr) * K + kc * 32 + sc * 8;
    bld[q] = smem + 16384 + b * 512;
  }

  f32x4 acc[4][4] = {};
  const int NT = K >> 6;                  // 32 K-tiles at BK=64

  // prologue: stage tile 0 -> buf0, tile 1 -> buf1 (6 loads/thread each)
#pragma unroll
  for (int q = 0; q < 4; ++q) { gl2lds16(agp[q], ald[q]);         agp[q] += 64; }
#pragma unroll
  for (int q = 0; q < 2; ++q) { gl2lds16(bgp[q], bld[q]);         bgp[q] += 64; }
#pragma unroll
  for (int q = 0; q < 4; ++q) { gl2lds16(agp[q], ald[q] + 24576); agp[q] += 64; }
#pragma unroll
  for (int q = 0; q < 2; ++q) { gl2lds16(bgp[q], bld[q] + 24576); bgp[q] += 64; }

  int cur = 0;                            // buffer holding tile tt
  for (int tt = 0; tt < NT; ++tt) {
    // gate: all but the newest 6 loads (tile tt+1's) must be done => tile tt landed.
    // Never drains to 0 except on the final tile (T4: counted vmcnt).
    if (tt + 1 < NT) asm volatile("s_waitcnt vmcnt(6)" ::: "memory");
    else             asm volatile("s_waitcnt vmcnt(0)" ::: "memory");
    __builtin_amdgcn_s_barrier();
    asm volatile("" ::: "memory");        // keep LDS reads below the barrier

    // issue tile tt+2's loads into buf (cur+2)%3 (last read at iter tt-1,
    // protected by that iteration's trailing barrier) — stays in flight
    // across both barriers of this iteration.
    if (tt + 2 < NT) {
      int nb = cur + 2; if (nb >= 3) nb -= 3;
      const int off = nb * 24576;
#pragma unroll
      for (int q = 0; q < 4; ++q) { gl2lds16(agp[q], ald[q] + off); agp[q] += 64; }
#pragma unroll
      for (int q = 0; q < 2; ++q) { gl2lds16(bgp[q], bld[q] + off); bgp[q] += 64; }
    }

    const u16* As = smem + cur * 24576;
    const u16* Bs = As + 16384;
#pragma unroll
    for (int kc = 0; kc < 2; ++kc) {
      bf16x8 af[4], bfv[4];
#pragma unroll
      for (int i = 0; i < 4; ++i)
        af[i] = *(const bf16x8*)&As[(kc * 16 + wm * 4 + i) * 512 + lane * 8];
#pragma unroll
      for (int j = 0; j < 4; ++j)
        bfv[j] = *(const bf16x8*)&Bs[(kc * 8 + wn * 4 + j) * 512 + lane * 8];
      __builtin_amdgcn_s_setprio(1);
#pragma unroll
      for (int i = 0; i < 4; ++i)
#pragma unroll
        for (int j = 0; j < 4; ++j)
          acc[i][j] = __builtin_amdgcn_mfma_f32_16x16x32_bf16(af[i], bfv[j], acc[i][j], 0, 0, 0);
      __builtin_amdgcn_s_setprio(0);
    }
    asm volatile("" ::: "memory");        // keep LDS reads above the barrier
    __builtin_amdgcn_s_barrier();         // frags consumed -> cur may be overwritten next iter
    cur = cur + 1; if (cur >= 3) cur -= 3;
  }

  if (mode == 0) {
    // ---- coalesced epilogue: LDS-stage fp32 tile, then float4 stores ----
    constexpr int LDW = 132;
    float* lf = (float*)smem;
#pragma unroll
    for (int i = 0; i < 4; ++i)
#pragma unroll
      for (int j = 0; j < 4; ++j)
#pragma unroll
        for (int rr = 0; rr < 4; ++rr) {
          int row = wm * 64 + i * 16 + quad * 4 + rr;
          int col = wn * 64 + j * 16 + l16;
          lf[row * LDW + col] = acc[i][j][rr];
        }
    __builtin_amdgcn_s_barrier();
    const int cg  = t & 31;               // 32 float4 groups cover 128 cols
    const int rw0 = t >> 5;               // 16 rows per pass
    float4 bv = *(const float4*)&bias[n0 + cg * 4];
#pragma unroll
    for (int ps = 0; ps < 16; ++ps) {
      int row = rw0 + ps * 16;
      const float* p = &lf[row * LDW + cg * 4];
      float4 v;
      v.x = p[0] + bv.x; v.y = p[1] + bv.y; v.z = p[2] + bv.z; v.w = p[3] + bv.w;
      *(float4*)&outf[(size_t)(m0 + row) * N + n0 + cg * 4] = v;
    }
  } else {
    // QKV scatter + fused RoPE. tens/h uniform per block (n0 % 128 == 0).
    const int tens = n0 >> 11;                 // 0=Q 1=K 2=V
    const int h    = (n0 & 2047) >> 7;
    const bool doRope = (tens < 2);
    const float mult = (tens == 0) ? 0.08838834764831845f : 1.0f;  // 1/sqrt(DK) on Q
#pragma unroll
    for (int j = 0; j < 4; ++j) {
      const int d = wn * 64 + j * 16 + l16;    // head-dim of this lane's column
      const float freq = exp2f(-0.20762050593045951f * (float)(d >> 1));
      const float sgn  = (d & 1) ? 1.f : -1.f;
#pragma unroll
      for (int i = 0; i < 4; ++i)
#pragma unroll
        for (int rr = 0; rr < 4; ++rr) {
          int row = m0 + wm * 64 + i * 16 + quad * 4 + rr;
          int b = row >> 11;
          int s = row & (SEQ - 1);
          float v = acc[i][j][rr];
          if (doRope) {
            float sn, cs;
            __sincosf((float)s * freq, &sn, &cs);
            float pv = __shfl_xor(v, 1);       // partner element of the (even,odd) pair
            v = (v * cs + sgn * pv * sn) * mult;
          }
          outb[(size_t)tens * 8388608 + (((size_t)(b * NHEADS + h)) * SEQ + s) * DK + d] = f2b(v);
        }
    }
  }
}

// ---------------- V transpose: (B,H,S,DK) -> (B,H,DK,S), bf16 ----------------
__global__ __launch_bounds__(256) void vt_k(const u16* __restrict__ V,
                                            u16* __restrict__ Vt) {
  constexpr int LDT = 72;
  __shared__ __align__(16) u16 tile[64 * LDT];
  const int s0 = blockIdx.x * 64, d0 = blockIdx.y * 64, bh = blockIdx.z;
  const u16* in = V + (size_t)bh * SEQ * DK;
  u16* out = Vt + (size_t)bh * DK * SEQ;
  const int t = threadIdx.x;
  const int r = t >> 3, cg = t & 7;
#pragma unroll
  for (int half = 0; half < 2; ++half) {
    uint4 v = *(const uint4*)(in + (size_t)(s0 + r + half * 32) * DK + d0 + cg * 8);
    *(uint4*)&tile[(r + half * 32) * LDT + cg * 8] = v;
  }
  __syncthreads();
#pragma unroll
  for (int half = 0; half < 2; ++half) {
    int d = (t >> 3) + half * 32;
    __align__(16) u16 tmp[8];
#pragma unroll
    for (int i = 0; i < 8; ++i) tmp[i] = tile[(cg * 8 + i) * LDT + d];
    *(uint4*)(out + (size_t)(d0 + d) * SEQ + s0 + cg * 8) = *(const uint4*)tmp;
  }
}

// ---------------- MFMA flash attention, causal, transposed-softmax ----------------
// Q: bf16 (B,H,S,DK), roped AND pre-scaled by 1/sqrt(DK). K: roped. Vt: (B,H,DK,S).
// out: bf16 (B,S,D_MODEL).
// R7: QBLK=128 (8 waves, 512 threads) — each staged K/V tile now serves 128
// query rows instead of 64: staged traffic 540 -> 278 MB and half the
// barrier/DMA phases, with BIT-IDENTICAL per-q-row math (lower waves skip
// the extra tail tile via the k0 >= qw+16 guard). LDS 48 KB; 16 waves/CU
// (VGPR-capped) — same occupancy as the old 4-wave x 4-block config.
__global__ __launch_bounds__(512, 4) void attn_k(const u16* __restrict__ Q,
                                                 const u16* __restrict__ K,
                                                 const u16* __restrict__ Vt,
                                                 u16* __restrict__ out) {
  __shared__ __align__(16) u16 smem[8192 + 8192 + 8192];  // Ks, Vs, P(8 waves) = 48KB
  u16* Ks = smem;              // 16 blocks of 512: (nt*4+kc), frag-major
  u16* Vs = smem + 8192;       // 16 blocks of 512: (kcp*8+nt), frag-major

  const int t    = threadIdx.x;
  const int lane = t & 63;
  const int wave = t >> 6;                      // 0..7
  const int quad = lane >> 4, l16 = lane & 15;
  u16* Psw = smem + 16384 + wave * 1024;        // 16q x 64k, swizzled
  const int pmask = (l16 & 7) << 3;             // XOR swizzle on key bits 3..5
  const int qt = (int)gridDim.x - 1 - (int)blockIdx.x;  // heavy blocks first
  const int bh = blockIdx.y;
  const size_t baseQK = (size_t)bh * SEQ * DK;
  const size_t baseV  = (size_t)bh * DK * SEQ;
  const int qw = qt * 128 + wave * 16;          // wave's first query row
  const int qglob = qw + l16;                   // this lane's query (transposed S)

  bf16x8 qf[4];
#pragma unroll
  for (int kc = 0; kc < 4; ++kc)
    qf[kc] = *(const bf16x8*)(Q + baseQK + (size_t)(qw + l16) * DK + kc * 32 + quad * 8);

  f32x4 oacc[8] = {};
  float m_run = -1e30f, l_run = 0.f;

  const int sr = lane & 15, sc = lane >> 4;
  const u16* kp[2]; u16* kd[2];
  const u16* vp[2]; u16* vd[2];
#pragma unroll
  for (int j = 0; j < 2; ++j) {
    int lin = wave * 2 + j;                     // 0..15
    int knt = lin >> 2, kkc = lin & 3;
    kp[j] = K + baseQK + (size_t)(knt * 16 + sr) * DK + kkc * 32 + sc * 8;
    kd[j] = Ks + lin * 512;
    int vkc = lin >> 3, vnt = lin & 7;
    vp[j] = Vt + baseV + (size_t)(vnt * 16 + sr) * SEQ + vkc * 32 + sc * 8;
    vd[j] = Vs + lin * 512;
  }

  const int kend = (qt + 1) * 128;
  for (int k0 = 0; k0 < kend; k0 += 64) {
    __syncthreads();
#pragma unroll
    for (int j = 0; j < 2; ++j) gl2lds16(kp[j], kd[j]);
#pragma unroll
    for (int j = 0; j < 2; ++j) gl2lds16(vp[j], vd[j]);
#pragma unroll
    for (int j = 0; j < 2; ++j) { kp[j] += (size_t)64 * DK; vp[j] += 64; }
    __syncthreads();

    if (k0 >= qw + 16) continue;        // wave-uniform causal skip (tail tiles)

    // ---- S^T = K . Q^T : 4 tiles of 16(key)x16(q) ----
    f32x4 s[4] = {};
#pragma unroll
    for (int kc = 0; kc < 4; ++kc) {
#pragma unroll
      for (int nt = 0; nt < 4; ++nt) {
        bf16x8 kf = *(const bf16x8*)&Ks[(nt * 4 + kc) * 512 + lane * 8];
        s[nt] = __builtin_amdgcn_mfma_f32_16x16x32_bf16(kf, qf[kc], s[nt], 0, 0, 0);
      }
    }

    // ---- softmax (lane holds 16 keys for q = qglob) ----
    float p[4][4];
    float newm = m_run;
    if (k0 + 63 > qw) {  // diagonal tile: per-lane causal mask (wave-uniform branch)
#pragma unroll
      for (int nt = 0; nt < 4; ++nt)
#pragma unroll
        for (int r = 0; r < 4; ++r) {
          int key = k0 + nt * 16 + quad * 4 + r;
          float v = (key <= qglob) ? s[nt][r] : -1e30f;
          p[nt][r] = v;
          newm = fmaxf(newm, v);
        }
    } else {
#pragma unroll
      for (int nt = 0; nt < 4; ++nt)
#pragma unroll
        for (int r = 0; r < 4; ++r) {
          p[nt][r] = s[nt][r];
          newm = fmaxf(newm, s[nt][r]);
        }
    }
    newm = fmaxf(newm, __shfl_xor(newm, 16));
    newm = fmaxf(newm, __shfl_xor(newm, 32));
    float lsum = 0.f;
#pragma unroll
    for (int nt = 0; nt < 4; ++nt)
#pragma unroll
      for (int r = 0; r < 4; ++r) {
        float e = __expf(p[nt][r] - newm);
        p[nt][r] = e;
        lsum += e;
      }
    lsum += __shfl_xor(lsum, 16);
    lsum += __shfl_xor(lsum, 32);
    float alpha = __expf(m_run - newm);
    l_run = l_run * alpha + lsum;
    m_run = newm;

    // ---- P^T write (swizzled, per-wave region; 4 b64 writes) ----
#pragma unroll
    for (int nt = 0; nt < 4; ++nt) {
      u32 lo = (u32)f2b(p[nt][0]) | ((u32)f2b(p[nt][1]) << 16);
      u32 hi = (u32)f2b(p[nt][2]) | ((u32)f2b(p[nt][3]) << 16);
      *(uint2*)&Psw[l16 * 64 + ((nt * 16 + quad * 4) ^ pmask)] = make_uint2(lo, hi);
    }

    // ---- rescale O accumulator ----
#pragma unroll
    for (int r = 0; r < 4; ++r) {
      float av = __shfl(alpha, quad * 4 + r);
#pragma unroll
      for (int nt = 0; nt < 8; ++nt) oacc[nt][r] *= av;
    }

    // ---- PV: O[q][d] += P . V^T ----
#pragma unroll
    for (int kcp = 0; kcp < 2; ++kcp) {
      bf16x8 pf = *(const bf16x8*)&Psw[l16 * 64 + ((kcp * 32 + quad * 8) ^ pmask)];
#pragma unroll
      for (int nt = 0; nt < 8; ++nt) {
        bf16x8 vf = *(const bf16x8*)&Vs[(kcp * 8 + nt) * 512 + lane * 8];
        oacc[nt] = __builtin_amdgcn_mfma_f32_16x16x32_bf16(pf, vf, oacc[nt], 0, 0, 0);
      }
    }
  }

  // ---- epilogue: normalize, stage to LDS, coalesced b128 store ----
  constexpr int LDO = 136;
  float invl = 1.f / l_run;
  __syncthreads();
#pragma unroll
  for (int r = 0; r < 4; ++r) {
    float iv = __shfl(invl, quad * 4 + r);
#pragma unroll
    for (int nt = 0; nt < 8; ++nt)
      smem[(wave * 16 + quad * 4 + r) * LDO + nt * 16 + l16] = f2b(oacc[nt][r] * iv);
  }
  __syncthreads();
  const int b = bh >> 4, h = bh & 15;
#pragma unroll
  for (int pss = 0; pss < 4; ++pss) {
    int row = (t >> 4) + pss * 32;                 // 128 rows, 512 threads
    uint4 v = *(const uint4*)&smem[row * LDO + (t & 15) * 8];
    *(uint4*)(out + ((size_t)(b * SEQ + qt * 128 + row)) * D_MODEL + h * DK + (t & 15) * 8) = v;
  }
}

// ---------------- host-side orchestration ----------------
extern "C" void kernel_launch(void* const* d_in, const int* in_sizes, int n_in,
                              void* d_out, int out_size, void* d_ws, size_t ws_size,
                              hipStream_t stream) {
  const float* x  = (const float*)d_in[0];
  const float* wq = (const float*)d_in[1];
  const float* wk = (const float*)d_in[2];
  const float* wv = (const float*)d_in[3];
  const float* wo = (const float*)d_in[4];
  const float* bo = (const float*)d_in[5];
  float* out = (float*)d_out;

  char* wsb = (char*)d_ws;
  u16* xb    = (u16*)(wsb + 0);          // 16.78 MB (reused as attn output later)
  u16* wqb   = (u16*)(wsb + 16777216);   //  8.39 MB (wq/wk/wv contiguous => fused B)
  u16* wkb   = (u16*)(wsb + 25165824);
  u16* wvb   = (u16*)(wsb + 33554432);
  u16* wob   = (u16*)(wsb + 41943040);
  u16* Qb    = (u16*)(wsb + 50331648);   // Q/K/V contiguous => fused scatter dest
  u16* Kb    = (u16*)(wsb + 67108864);
  u16* Vb    = (u16*)(wsb + 83886080);
  u16* attnb = xb;                       // x's bf16 copy dead after QKV GEMM
  u16* Vtb   = wqb;                      // weights dead after QKV GEMM (16.78 MB span)

  // 1) convert inputs to bf16
  cvt_k<<<8192, 256, 0, stream>>>(x, xb, MTOT * D_MODEL / 4);
  cvt4_k<<<dim3(4096, 4), 256, 0, stream>>>(wq, wk, wv, wo, wqb, wkb, wvb, wob,
                                            D_MODEL * D_MODEL / 4);

  // 2) fused Q/K/V projection + RoPE (+Q scale): one GEMM, N=6144
  //    grid: 48 x 16 = 768 blocks = exactly 3 rounds of 256 CU
  gemm256<<<dim3(48, 16), 512, 0, stream>>>(xb, wqb, MTOT, 3 * D_MODEL, D_MODEL,
                                            Qb, nullptr, nullptr, 1);

  // 3) V transpose to (B,H,DK,S)
  vt_k<<<dim3(SEQ / 64, DK / 64, BATCH * NHEADS), 256, 0, stream>>>(Vb, Vtb);

  // 4) causal MFMA flash attention -> (B,S,D_MODEL) bf16
  //    grid: 16 q-tiles (QBLK=128) x 32 bh = 512 blocks, 512 threads
  attn_k<<<dim3(SEQ / 128, BATCH * NHEADS), 512, 0, stream>>>(Qb, Kb, Vtb, attnb);

  // 5) output projection + bias -> fp32 d_out
  //    grid: 16 x 16 = 256 blocks = exactly 1 round
  gemm256<<<dim3(16, 16), 512, 0, stream>>>(attnb, wob, MTOT, D_MODEL, D_MODEL,
                                            nullptr, out, bo, 0);
}